// Round 1
// baseline (721.274 us; speedup 1.0000x reference)
//
#include <hip/hip_runtime.h>

typedef _Float16 f16x8 __attribute__((ext_vector_type(8)));
typedef float f32x4 __attribute__((ext_vector_type(4)));
typedef unsigned int u32;

#define ROWS 64
#define THREADS 512

// ---------------------------------------------------------------------------
// Prep: convert W1/W2/W3 (f32, [K][C] row-major) into f16 fragment-linear
// layout WF[ct][kt][lane][8], applying block-diag masks by only gathering
// in-block K. Fragment mapping for mfma_f32_16x16x32_f16 B-operand:
//   col = ct*16 + (lane&15), k = kbase + kt*32 + (lane>>4)*8 + j
// ---------------------------------------------------------------------------
__global__ __launch_bounds__(512) void pack_weights(
    const float* __restrict__ W1, const float* __restrict__ W2,
    const float* __restrict__ W3, _Float16* __restrict__ WF1,
    _Float16* __restrict__ WF2, _Float16* __restrict__ WF3) {
  int t = blockIdx.x * 512 + threadIdx.x;
  const float* src; _Float16* dst; int idx, ct, kt, lane, kbase;
  if (t < 131072) {                       // W1: 64 ct * 32 kt * 64 lanes
    idx = t; src = W1; dst = WF1;
    ct = idx >> 11; kt = (idx >> 6) & 31; lane = idx & 63; kbase = 0;
  } else if (t < 196608) {                // W2: 64 ct * 16 kt * 64 lanes
    idx = t - 131072; src = W2; dst = WF2;
    ct = idx >> 10; kt = (idx >> 6) & 15; lane = idx & 63;
    kbase = (ct >= 32) ? 512 : 0;         // 2 blocks of 512
  } else {                                // W3: 64 ct * 8 kt * 64 lanes
    idx = t - 196608; src = W3; dst = WF3;
    ct = idx >> 9; kt = (idx >> 6) & 7; lane = idx & 63;
    kbase = (ct >> 4) << 8;               // 4 blocks of 256
  }
  int c  = ct * 16 + (lane & 15);
  int k0 = kbase + kt * 32 + ((lane >> 4) << 3);
  f16x8 v;
#pragma unroll
  for (int j = 0; j < 8; ++j) v[j] = (_Float16)src[(size_t)(k0 + j) * 1024 + c];
  *reinterpret_cast<f16x8*>(dst + (size_t)idx * 8) = v;
}

// ---------------------------------------------------------------------------
// One MFMA layer: h (LDS, f16, XOR-swizzled) @ WF -> sin(.+bias) -> h in-place
// Wave wid owns cols [wid*128, wid*128+128); acc tile 4(m) x 8(n) frags.
// A-frag: row = m*16 + (lane&15), k = kt*32 + (lane>>4)*8 + j   (ds_read_b128)
// C/D:    col = lane&15, row = (lane>>4)*4 + i                  (measured m89)
// ---------------------------------------------------------------------------
template <int KT>
__device__ __forceinline__ void layer_mfma(char* hb, const _Float16* __restrict__ WF,
                                           const float* __restrict__ bias,
                                           int wid, int lane, int kbase) {
  f32x4 acc[4][8];
#pragma unroll
  for (int m = 0; m < 4; ++m)
#pragma unroll
    for (int n = 0; n < 8; ++n) acc[m][n] = f32x4{0.f, 0.f, 0.f, 0.f};

  const f16x8* wf = reinterpret_cast<const f16x8*>(WF) +
                    (size_t)wid * 8 * KT * 64 + lane;
  const int arow = lane & 15;
  const int koff = (lane >> 4) << 3;
  const u32 abase = (u32)(arow * 2048);
  const u32 axor  = (u32)((arow & 7) << 4);   // (row&7) == (arow&7), m*16 ≡ 0 mod 8

  f16x8 bA[8], bB[8];
#define LOADB(buf, ktv)                                                        \
  { int _kt = (ktv);                                                           \
    _Pragma("unroll") for (int n = 0; n < 8; ++n)                              \
      buf[n] = wf[(size_t)n * KT * 64 + (size_t)_kt * 64]; }
#define DOMFMA(buf, ktv)                                                       \
  { int _kt = (ktv);                                                           \
    u32 kb = (u32)((kbase + _kt * 32 + koff) * 2);                             \
    f16x8 a[4];                                                                \
    _Pragma("unroll") for (int m = 0; m < 4; ++m) {                            \
      u32 addr = ((u32)(m * 16 * 2048) + abase + kb) ^ axor;                   \
      a[m] = *reinterpret_cast<const f16x8*>(hb + addr);                       \
    }                                                                          \
    _Pragma("unroll") for (int m = 0; m < 4; ++m)                              \
      _Pragma("unroll") for (int n = 0; n < 8; ++n)                            \
        acc[m][n] = __builtin_amdgcn_mfma_f32_16x16x32_f16(a[m], buf[n],       \
                                                           acc[m][n], 0, 0, 0); }

  LOADB(bA, 0);
#pragma unroll 1
  for (int kt = 0; kt < KT; kt += 2) {      // 2-phase manual B double-buffer
    LOADB(bB, kt + 1);
    DOMFMA(bA, kt);
    LOADB(bA, (kt + 2 < KT) ? (kt + 2) : 0);
    DOMFMA(bB, kt + 1);
  }
#undef LOADB
#undef DOMFMA

  __syncthreads();                          // all waves done READING h
  const int ccol = lane & 15;
  const int rsub = (lane >> 4) << 2;
#pragma unroll
  for (int n = 0; n < 8; ++n) {
    int c = wid * 128 + n * 16 + ccol;
    float bb = bias[c];
#pragma unroll
    for (int m = 0; m < 4; ++m)
#pragma unroll
      for (int i = 0; i < 4; ++i) {
        int row = m * 16 + rsub + i;
        float v = __sinf(acc[m][n][i] + bb);
        u32 addr = ((u32)(row * 2048 + c * 2)) ^ ((u32)(row & 7) << 4);
        *reinterpret_cast<_Float16*>(hb + addr) = (_Float16)v;
      }
  }
  __syncthreads();                          // h_out visible before next layer
}

// ---------------------------------------------------------------------------
// Fused forward: 64 rows per WG, h lives in LDS for the whole network.
// ---------------------------------------------------------------------------
__global__ __launch_bounds__(THREADS, 2) void bspinn_fused(
    const float* __restrict__ X, const float* __restrict__ lb,
    const float* __restrict__ ub,
    const float* __restrict__ W0, const float* __restrict__ b0,
    const _Float16* __restrict__ WF1, const float* __restrict__ b1,
    const _Float16* __restrict__ WF2, const float* __restrict__ b2,
    const _Float16* __restrict__ WF3, const float* __restrict__ b3,
    const float* __restrict__ W4, const float* __restrict__ b4,
    float* __restrict__ out) {
  __shared__ alignas(16) char hb[ROWS * 2048];   // 128 KiB, f16, swizzled
  __shared__ float xs[ROWS * 4];
  __shared__ float partials[ROWS * 8];

  const int tid  = threadIdx.x;
  const int lane = tid & 63;
  const int wid  = tid >> 6;
  const int r0   = blockIdx.x * ROWS;

  if (tid < ROWS * 3) {                      // stage + normalize X
    int r = tid / 3, j = tid - r * 3;
    float x = X[(size_t)r0 * 3 + tid];
    xs[r * 4 + j] = 2.0f * (x - lb[j]) / (ub[j] - lb[j]) - 1.0f;
  }
  __syncthreads();

  // ---- layer 1 (K=3, VALU): each thread owns 2 cols x 64 rows ----
  {
    int c0 = tid * 2;
    float wa0 = W0[c0],        wb0 = W0[c0 + 1];
    float wa1 = W0[1024 + c0], wb1 = W0[1025 + c0];
    float wa2 = W0[2048 + c0], wb2 = W0[2049 + c0];
    float ba = b0[c0], bbv = b0[c0 + 1];
#pragma unroll 4
    for (int r = 0; r < ROWS; ++r) {
      float x0 = xs[r * 4], x1 = xs[r * 4 + 1], x2 = xs[r * 4 + 2];
      float va = __sinf(fmaf(x2, wa2, fmaf(x1, wa1, fmaf(x0, wa0, ba))));
      float vb = __sinf(fmaf(x2, wb2, fmaf(x1, wb1, fmaf(x0, wb0, bbv))));
      union { _Float16 h2[2]; u32 u; } pk;
      pk.h2[0] = (_Float16)va; pk.h2[1] = (_Float16)vb;
      u32 addr = ((u32)(r * 2048 + c0 * 2)) ^ ((u32)(r & 7) << 4);
      *reinterpret_cast<u32*>(hb + addr) = pk.u;
    }
  }
  __syncthreads();

  layer_mfma<32>(hb, WF1, b1, wid, lane, 0);                  // dense 1024
  layer_mfma<16>(hb, WF2, b2, wid, lane, (wid >> 2) * 512);   // 2 blocks
  layer_mfma<8 >(hb, WF3, b3, wid, lane, (wid >> 1) * 256);   // 4 blocks

  // ---- layer 5 (M=1, VALU): lane = row -> conflict-free swizzled reads ----
  {
    int r = lane, seg = wid;
    u32 rb = (u32)(r * 2048);
    u32 xr = (u32)((r & 7) << 4);
    float s = 0.f;
#pragma unroll
    for (int kk = 0; kk < 128; kk += 8) {
      int k = seg * 128 + kk;
      f16x8 v = *reinterpret_cast<const f16x8*>(hb + ((rb + (u32)(k * 2)) ^ xr));
#pragma unroll
      for (int j = 0; j < 8; ++j) s = fmaf((float)v[j], W4[k + j], s);
    }
    partials[seg * 64 + r] = s;
  }
  __syncthreads();
  if (tid < ROWS) {
    float s = b4[0];
#pragma unroll
    for (int g = 0; g < 8; ++g) s += partials[g * 64 + tid];
    out[r0 + tid] = s;
  }
}

extern "C" void kernel_launch(void* const* d_in, const int* in_sizes, int n_in,
                              void* d_out, int out_size, void* d_ws, size_t ws_size,
                              hipStream_t stream) {
  const float* X  = (const float*)d_in[0];
  const float* lb = (const float*)d_in[1];
  const float* ub = (const float*)d_in[2];
  const float* W0 = (const float*)d_in[3];
  const float* b0 = (const float*)d_in[4];
  const float* W1 = (const float*)d_in[5];
  const float* b1 = (const float*)d_in[6];
  const float* W2 = (const float*)d_in[7];
  const float* b2 = (const float*)d_in[8];
  const float* W3 = (const float*)d_in[9];
  const float* b3 = (const float*)d_in[10];
  const float* W4 = (const float*)d_in[11];
  const float* b4 = (const float*)d_in[12];
  float* out = (float*)d_out;

  _Float16* WF1 = (_Float16*)d_ws;                                    // 2 MiB
  _Float16* WF2 = (_Float16*)((char*)d_ws + 2097152);                 // 1 MiB
  _Float16* WF3 = (_Float16*)((char*)d_ws + 2097152 + 1048576);       // 512 KiB

  hipLaunchKernelGGL(pack_weights, dim3(448), dim3(512), 0, stream,
                     W1, W2, W3, WF1, WF2, WF3);
  hipLaunchKernelGGL(bspinn_fused, dim3(131072 / ROWS), dim3(THREADS), 0, stream,
                     X, lb, ub, W0, b0, WF1, b1, WF2, b2, WF3, b3, W4, b4, out);
}

// Round 2
// 521.107 us; speedup vs baseline: 1.3841x; 1.3841x over previous
//
#include <hip/hip_runtime.h>

typedef _Float16 f16x8 __attribute__((ext_vector_type(8)));
typedef _Float16 f16x4 __attribute__((ext_vector_type(4)));
typedef float f32x4 __attribute__((ext_vector_type(4)));
typedef unsigned int u32;

#define ROWS 64
#define THREADS 512

// ---------------------------------------------------------------------------
// Prep: convert W1/W2/W3 (f32, [K][C] row-major) into f16 fragment-linear
// layout WF[ct][kt][lane][8], applying block-diag masks by only gathering
// in-block K. Fragment mapping (used as MFMA *A* operand, M-dim = out col):
//   col = ct*16 + (lane&15), k = kbase + kt*32 + (lane>>4)*8 + j
// ---------------------------------------------------------------------------
__global__ __launch_bounds__(512) void pack_weights(
    const float* __restrict__ W1, const float* __restrict__ W2,
    const float* __restrict__ W3, _Float16* __restrict__ WF1,
    _Float16* __restrict__ WF2, _Float16* __restrict__ WF3) {
  int t = blockIdx.x * 512 + threadIdx.x;
  const float* src; _Float16* dst; int idx, ct, kt, lane, kbase;
  if (t < 131072) {                       // W1: 64 ct * 32 kt * 64 lanes
    idx = t; src = W1; dst = WF1;
    ct = idx >> 11; kt = (idx >> 6) & 31; lane = idx & 63; kbase = 0;
  } else if (t < 196608) {                // W2: 64 ct * 16 kt * 64 lanes
    idx = t - 131072; src = W2; dst = WF2;
    ct = idx >> 10; kt = (idx >> 6) & 15; lane = idx & 63;
    kbase = (ct >= 32) ? 512 : 0;         // 2 blocks of 512
  } else {                                // W3: 64 ct * 8 kt * 64 lanes
    idx = t - 196608; src = W3; dst = WF3;
    ct = idx >> 9; kt = (idx >> 6) & 7; lane = idx & 63;
    kbase = (ct >> 4) << 8;               // 4 blocks of 256
  }
  int c  = ct * 16 + (lane & 15);
  int k0 = kbase + kt * 32 + ((lane >> 4) << 3);
  f16x8 v;
#pragma unroll
  for (int j = 0; j < 8; ++j) v[j] = (_Float16)src[(size_t)(k0 + j) * 1024 + c];
  *reinterpret_cast<f16x8*>(dst + (size_t)idx * 8) = v;
}

// ---------------------------------------------------------------------------
// One MFMA layer, TRANSPOSED operand order: D = W_frag * h_frag.
//   A (W): M-dim = out col,  row = lane&15, k = kt*32+(lane>>4)*8+j
//   B (h): N-dim = data row, col = lane&15, same k mapping (ds_read_b128)
//   D:     col(lane&15) = data row r, row((lane>>4)*4+i) = out col c
// => lane holds 4 CONSECUTIVE out-cols per frag -> packed ds_write_b64.
// Wave wid owns out-cols [wid*128, +128): acc[8 cf][4 rf].
// ---------------------------------------------------------------------------
template <int KT>
__device__ __forceinline__ void layer_mfma(char* hb, const _Float16* __restrict__ WF,
                                           const float* __restrict__ bias,
                                           int wid, int lane, int kbase) {
  f32x4 acc[8][4];
#pragma unroll
  for (int cf = 0; cf < 8; ++cf)
#pragma unroll
    for (int rf = 0; rf < 4; ++rf) acc[cf][rf] = f32x4{0.f, 0.f, 0.f, 0.f};

  const f16x8* wf = reinterpret_cast<const f16x8*>(WF) +
                    (u32)(wid * 8 * KT * 64 + lane);
  const int arow = lane & 15;
  const int koff = (lane >> 4) << 3;
  const u32 abase = (u32)(arow * 2048);
  const u32 axor  = (u32)((arow & 7) << 4);   // (row&7)==(arow&7): rf*16 ≡ 0 mod 8

  f16x8 wA[8], wB[8];
#define LOADW(buf, ktv)                                                        \
  { u32 _kt = (u32)(ktv);                                                      \
    _Pragma("unroll") for (int cf = 0; cf < 8; ++cf)                           \
      buf[cf] = wf[(u32)(cf * KT) * 64u + _kt * 64u]; }
#define DOMFMA(buf, ktv)                                                       \
  { int _kt = (ktv);                                                           \
    u32 kb = (u32)((kbase + _kt * 32 + koff) * 2);                             \
    f16x8 h[4];                                                                \
    _Pragma("unroll") for (int rf = 0; rf < 4; ++rf) {                         \
      u32 addr = ((u32)(rf * 32768) + abase + kb) ^ axor;                      \
      h[rf] = *reinterpret_cast<const f16x8*>(hb + addr);                      \
    }                                                                          \
    _Pragma("unroll") for (int cf = 0; cf < 8; ++cf)                           \
      _Pragma("unroll") for (int rf = 0; rf < 4; ++rf)                         \
        acc[cf][rf] = __builtin_amdgcn_mfma_f32_16x16x32_f16(buf[cf], h[rf],   \
                                                             acc[cf][rf], 0, 0, 0); }

  LOADW(wA, 0);
#pragma unroll 1
  for (int kt = 0; kt < KT; kt += 2) {      // 2-phase manual W double-buffer
    LOADW(wB, kt + 1);
    DOMFMA(wA, kt);
    LOADW(wA, (kt + 2 < KT) ? (kt + 2) : 0);
    DOMFMA(wB, kt + 1);
  }
#undef LOADW
#undef DOMFMA

  __syncthreads();                          // all waves done READING h
  const int csub = (lane >> 4) << 2;        // 0,4,8,12
  const int rr   = lane & 15;
#pragma unroll
  for (int cf = 0; cf < 8; ++cf) {
    int c0 = wid * 128 + cf * 16 + csub;
    f32x4 bb = *reinterpret_cast<const f32x4*>(bias + c0);
#pragma unroll
    for (int rf = 0; rf < 4; ++rf) {
      int r = rf * 16 + rr;
      f16x4 pk;
#pragma unroll
      for (int i = 0; i < 4; ++i) pk[i] = (_Float16)__sinf(acc[cf][rf][i] + bb[i]);
      u32 addr = ((u32)(r * 2048 + c0 * 2)) ^ ((u32)((r & 7) << 4));
      *reinterpret_cast<f16x4*>(hb + addr) = pk;
    }
  }
  __syncthreads();                          // h_out visible before next layer
}

// ---------------------------------------------------------------------------
// Fused forward: 64 rows per WG, h lives in LDS for the whole network.
// ---------------------------------------------------------------------------
__global__
__attribute__((amdgpu_flat_work_group_size(512, 512), amdgpu_waves_per_eu(2, 2)))
void bspinn_fused(
    const float* __restrict__ X, const float* __restrict__ lb,
    const float* __restrict__ ub,
    const float* __restrict__ W0, const float* __restrict__ b0,
    const _Float16* __restrict__ WF1, const float* __restrict__ b1,
    const _Float16* __restrict__ WF2, const float* __restrict__ b2,
    const _Float16* __restrict__ WF3, const float* __restrict__ b3,
    const float* __restrict__ W4, const float* __restrict__ b4,
    float* __restrict__ out) {
  __shared__ alignas(16) char hb[ROWS * 2048];   // 128 KiB, f16, swizzled
  __shared__ float xs[ROWS * 4];
  __shared__ float partials[ROWS * 8];

  const int tid  = threadIdx.x;
  const int lane = tid & 63;
  const int wid  = tid >> 6;
  const int r0   = blockIdx.x * ROWS;

  if (tid < ROWS * 3) {                      // stage + normalize X
    int r = tid / 3, j = tid - r * 3;
    float x = X[(size_t)r0 * 3 + tid];
    xs[r * 4 + j] = 2.0f * (x - lb[j]) / (ub[j] - lb[j]) - 1.0f;
  }
  __syncthreads();

  // ---- layer 1 (K=3, VALU): each thread owns 2 cols x 64 rows ----
  {
    int c0 = tid * 2;
    float wa0 = W0[c0],        wb0 = W0[c0 + 1];
    float wa1 = W0[1024 + c0], wb1 = W0[1025 + c0];
    float wa2 = W0[2048 + c0], wb2 = W0[2049 + c0];
    float ba = b0[c0], bbv = b0[c0 + 1];
#pragma unroll 4
    for (int r = 0; r < ROWS; ++r) {
      float x0 = xs[r * 4], x1 = xs[r * 4 + 1], x2 = xs[r * 4 + 2];
      float va = __sinf(fmaf(x2, wa2, fmaf(x1, wa1, fmaf(x0, wa0, ba))));
      float vb = __sinf(fmaf(x2, wb2, fmaf(x1, wb1, fmaf(x0, wb0, bbv))));
      union { _Float16 h2[2]; u32 u; } pk;
      pk.h2[0] = (_Float16)va; pk.h2[1] = (_Float16)vb;
      u32 addr = ((u32)(r * 2048 + c0 * 2)) ^ ((u32)((r & 7) << 4));
      *reinterpret_cast<u32*>(hb + addr) = pk.u;
    }
  }
  __syncthreads();

  layer_mfma<32>(hb, WF1, b1, wid, lane, 0);                  // dense 1024
  layer_mfma<16>(hb, WF2, b2, wid, lane, (wid >> 2) * 512);   // 2 blocks
  layer_mfma<8 >(hb, WF3, b3, wid, lane, (wid >> 1) * 256);   // 4 blocks

  // ---- layer 5 (M=1, VALU): lane = row -> swizzled reads, W4 via s-loads ----
  {
    int r = lane, seg = wid;
    u32 rb = (u32)(r * 2048);
    u32 xr = (u32)((r & 7) << 4);
    float s = 0.f;
#pragma unroll
    for (int kk = 0; kk < 128; kk += 8) {
      int k = seg * 128 + kk;
      f16x8 v = *reinterpret_cast<const f16x8*>(hb + ((rb + (u32)(k * 2)) ^ xr));
#pragma unroll
      for (int j = 0; j < 8; ++j) s = fmaf((float)v[j], W4[k + j], s);
    }
    partials[seg * 64 + r] = s;
  }
  __syncthreads();
  if (tid < ROWS) {
    float s = b4[0];
#pragma unroll
    for (int g = 0; g < 8; ++g) s += partials[g * 64 + tid];
    out[r0 + tid] = s;
  }
}

extern "C" void kernel_launch(void* const* d_in, const int* in_sizes, int n_in,
                              void* d_out, int out_size, void* d_ws, size_t ws_size,
                              hipStream_t stream) {
  const float* X  = (const float*)d_in[0];
  const float* lb = (const float*)d_in[1];
  const float* ub = (const float*)d_in[2];
  const float* W0 = (const float*)d_in[3];
  const float* b0 = (const float*)d_in[4];
  const float* W1 = (const float*)d_in[5];
  const float* b1 = (const float*)d_in[6];
  const float* W2 = (const float*)d_in[7];
  const float* b2 = (const float*)d_in[8];
  const float* W3 = (const float*)d_in[9];
  const float* b3 = (const float*)d_in[10];
  const float* W4 = (const float*)d_in[11];
  const float* b4 = (const float*)d_in[12];
  float* out = (float*)d_out;

  _Float16* WF1 = (_Float16*)d_ws;                                    // 2 MiB
  _Float16* WF2 = (_Float16*)((char*)d_ws + 2097152);                 // 1 MiB
  _Float16* WF3 = (_Float16*)((char*)d_ws + 2097152 + 1048576);       // 512 KiB

  hipLaunchKernelGGL(pack_weights, dim3(448), dim3(512), 0, stream,
                     W1, W2, W3, WF1, WF2, WF3);
  hipLaunchKernelGGL(bspinn_fused, dim3(131072 / ROWS), dim3(THREADS), 0, stream,
                     X, lb, ub, W0, b0, WF1, b1, WF2, b2, WF3, b3, W4, b4, out);
}

// Round 5
// 491.370 us; speedup vs baseline: 1.4679x; 1.0605x over previous
//
#include <hip/hip_runtime.h>

typedef _Float16 f16x8 __attribute__((ext_vector_type(8)));
typedef _Float16 f16x4 __attribute__((ext_vector_type(4)));
typedef __fp16  fp16x2 __attribute__((ext_vector_type(2)));
typedef float f32x4 __attribute__((ext_vector_type(4)));
typedef unsigned int u32;

#define ROWS 64
#define THREADS 512

// ---------------------------------------------------------------------------
// Prep: convert W1/W2/W3 (f32, [K][C] row-major) into f16 fragment-linear
// layout WF[ct][kt][lane][8], applying block-diag masks by only gathering
// in-block K. Fragment mapping (used as MFMA *A* operand, M-dim = out col):
//   col = ct*16 + (lane&15), k = kbase + kt*32 + (lane>>4)*8 + j
// ---------------------------------------------------------------------------
__global__ __launch_bounds__(512) void pack_weights(
    const float* __restrict__ W1, const float* __restrict__ W2,
    const float* __restrict__ W3, _Float16* __restrict__ WF1,
    _Float16* __restrict__ WF2, _Float16* __restrict__ WF3) {
  int t = blockIdx.x * 512 + threadIdx.x;
  const float* src; _Float16* dst; int idx, ct, kt, lane, kbase;
  if (t < 131072) {                       // W1: 64 ct * 32 kt * 64 lanes
    idx = t; src = W1; dst = WF1;
    ct = idx >> 11; kt = (idx >> 6) & 31; lane = idx & 63; kbase = 0;
  } else if (t < 196608) {                // W2: 64 ct * 16 kt * 64 lanes
    idx = t - 131072; src = W2; dst = WF2;
    ct = idx >> 10; kt = (idx >> 6) & 15; lane = idx & 63;
    kbase = (ct >= 32) ? 512 : 0;         // 2 blocks of 512
  } else {                                // W3: 64 ct * 8 kt * 64 lanes
    idx = t - 196608; src = W3; dst = WF3;
    ct = idx >> 9; kt = (idx >> 6) & 7; lane = idx & 63;
    kbase = (ct >> 4) << 8;               // 4 blocks of 256
  }
  int c  = ct * 16 + (lane & 15);
  int k0 = kbase + kt * 32 + ((lane >> 4) << 3);
  f16x8 v;
#pragma unroll
  for (int j = 0; j < 8; ++j) v[j] = (_Float16)src[(size_t)(k0 + j) * 1024 + c];
  *reinterpret_cast<f16x8*>(dst + (size_t)idx * 8) = v;
}

// ---------------------------------------------------------------------------
// One MFMA layer, TRANSPOSED operand order: D = W_frag * h_frag.
//   A (W): M-dim = out col,  row = lane&15, k = kt*32+(lane>>4)*8+j
//   B (h): N-dim = data row, col = lane&15, same k mapping (ds_read_b128)
//   D:     col(lane&15) = data row r, row((lane>>4)*4+i) = out col c
// Wave wid owns out-cols [wid*128, +128): acc[8 cf][4 rf].
// K-loop is software-pipelined 1 phase deep on BOTH operands (W dbuf via
// global->reg, h dbuf via ds_read->reg) so the compiler emits counted
// vmcnt/lgkmcnt waits instead of full drains. No barrier inside the loop.
// ---------------------------------------------------------------------------
template <int KT>
__device__ __forceinline__ void layer_mfma(char* hb, const _Float16* __restrict__ WF,
                                           const float* __restrict__ bias,
                                           int wid, int lane, int kbase) {
  f32x4 acc[8][4];
#pragma unroll
  for (int cf = 0; cf < 8; ++cf)
#pragma unroll
    for (int rf = 0; rf < 4; ++rf) acc[cf][rf] = f32x4{0.f, 0.f, 0.f, 0.f};

  const f16x8* wf = reinterpret_cast<const f16x8*>(WF) +
                    (u32)(wid * 8 * KT * 64 + lane);
  const int arow = lane & 15;
  const int koff = (lane >> 4) << 3;
  const u32 abase = (u32)(arow * 2048);
  const u32 axor  = (u32)((arow & 7) << 4);   // (row&7)==(arow&7): rf*16 ≡ 0 mod 8

  f16x8 wA[8], wB[8], hA[4], hB[4];
#define LOADW(buf, ktv)                                                        \
  { u32 _kt = (u32)(ktv);                                                      \
    _Pragma("unroll") for (int cf = 0; cf < 8; ++cf)                           \
      buf[cf] = wf[(u32)(cf * KT) * 64u + _kt * 64u]; }
#define LDH(buf, ktv)                                                          \
  { u32 kb = (u32)((kbase + (ktv) * 32 + koff) * 2);                           \
    _Pragma("unroll") for (int rf = 0; rf < 4; ++rf) {                         \
      u32 addr = ((u32)(rf * 32768) + abase + kb) ^ axor;                      \
      buf[rf] = *reinterpret_cast<const f16x8*>(hb + addr);                    \
    } }
#define DOMFMA(w, h)                                                           \
  { __builtin_amdgcn_s_setprio(1);                                             \
    _Pragma("unroll") for (int cf = 0; cf < 8; ++cf)                           \
      _Pragma("unroll") for (int rf = 0; rf < 4; ++rf)                         \
        acc[cf][rf] = __builtin_amdgcn_mfma_f32_16x16x32_f16(w[cf], h[rf],     \
                                                             acc[cf][rf], 0, 0, 0); \
    __builtin_amdgcn_s_setprio(0); }

  LOADW(wA, 0);
  LDH(hA, 0);
#pragma unroll 1
  for (int kt = 0; kt < KT; kt += 2) {
    int ktn = (kt + 2 < KT) ? (kt + 2) : 0;
    LOADW(wB, kt + 1);                    // issue next-phase loads first
    LDH(hB, kt + 1);
    DOMFMA(wA, hA);                       // waits: vmcnt(8) lgkmcnt(4)
    LOADW(wA, ktn);
    LDH(hA, ktn);
    DOMFMA(wB, hB);
  }
#undef LOADW
#undef LDH
#undef DOMFMA

  __syncthreads();                          // all waves done READING h
  const int csub = (lane >> 4) << 2;        // 0,4,8,12
  const int rr   = lane & 15;
#pragma unroll
  for (int cf = 0; cf < 8; ++cf) {
    int c0 = wid * 128 + cf * 16 + csub;
    f32x4 bb = *reinterpret_cast<const f32x4*>(bias + c0);
#pragma unroll
    for (int rf = 0; rf < 4; ++rf) {
      int r = rf * 16 + rr;
      float s0 = __sinf(acc[cf][rf][0] + bb[0]);
      float s1 = __sinf(acc[cf][rf][1] + bb[1]);
      float s2 = __sinf(acc[cf][rf][2] + bb[2]);
      float s3 = __sinf(acc[cf][rf][3] + bb[3]);
      union { fp16x2 h2[2]; f16x4 v; } pk;
      pk.h2[0] = __builtin_amdgcn_cvt_pkrtz(s0, s1);
      pk.h2[1] = __builtin_amdgcn_cvt_pkrtz(s2, s3);
      u32 addr = ((u32)(r * 2048 + c0 * 2)) ^ ((u32)((r & 7) << 4));
      *reinterpret_cast<f16x4*>(hb + addr) = pk.v;
    }
  }
  __syncthreads();                          // h_out visible before next layer
}

// ---------------------------------------------------------------------------
// Fused forward: 64 rows per WG, h lives in LDS for the whole network.
// ---------------------------------------------------------------------------
__global__
__attribute__((amdgpu_flat_work_group_size(512, 512), amdgpu_waves_per_eu(2, 2)))
void bspinn_fused(
    const float* __restrict__ X, const float* __restrict__ lb,
    const float* __restrict__ ub,
    const float* __restrict__ W0, const float* __restrict__ b0,
    const _Float16* __restrict__ WF1, const float* __restrict__ b1,
    const _Float16* __restrict__ WF2, const float* __restrict__ b2,
    const _Float16* __restrict__ WF3, const float* __restrict__ b3,
    const float* __restrict__ W4, const float* __restrict__ b4,
    float* __restrict__ out) {
  __shared__ alignas(16) char hb[ROWS * 2048];   // 128 KiB, f16, swizzled
  __shared__ float xs[ROWS * 4];
  __shared__ float partials[ROWS * 8];

  const int tid  = threadIdx.x;
  const int lane = tid & 63;
  const int wid  = tid >> 6;
  const int r0   = blockIdx.x * ROWS;

  if (tid < ROWS * 3) {                      // stage + normalize X
    int r = tid / 3, j = tid - r * 3;
    float x = X[(size_t)r0 * 3 + tid];
    xs[r * 4 + j] = 2.0f * (x - lb[j]) / (ub[j] - lb[j]) - 1.0f;
  }
  __syncthreads();

  // ---- layer 1 (K=3, VALU): each thread owns 2 cols x 64 rows ----
  {
    int c0 = tid * 2;
    float wa0 = W0[c0],        wb0 = W0[c0 + 1];
    float wa1 = W0[1024 + c0], wb1 = W0[1025 + c0];
    float wa2 = W0[2048 + c0], wb2 = W0[2049 + c0];
    float ba = b0[c0], bbv = b0[c0 + 1];
#pragma unroll 4
    for (int r = 0; r < ROWS; ++r) {
      float x0 = xs[r * 4], x1 = xs[r * 4 + 1], x2 = xs[r * 4 + 2];
      float va = __sinf(fmaf(x2, wa2, fmaf(x1, wa1, fmaf(x0, wa0, ba))));
      float vb = __sinf(fmaf(x2, wb2, fmaf(x1, wb1, fmaf(x0, wb0, bbv))));
      union { fp16x2 h2; u32 u; } pk;
      pk.h2 = __builtin_amdgcn_cvt_pkrtz(va, vb);
      u32 addr = ((u32)(r * 2048 + c0 * 2)) ^ ((u32)((r & 7) << 4));
      *reinterpret_cast<u32*>(hb + addr) = pk.u;
    }
  }
  __syncthreads();

  layer_mfma<32>(hb, WF1, b1, wid, lane, 0);                  // dense 1024
  layer_mfma<16>(hb, WF2, b2, wid, lane, (wid >> 2) * 512);   // 2 blocks
  layer_mfma<8 >(hb, WF3, b3, wid, lane, (wid >> 1) * 256);   // 4 blocks

  // ---- layer 5 (M=1, VALU): lane = row -> swizzled conflict-light reads ----
  {
    int r = lane, seg = wid;
    u32 rb = (u32)(r * 2048);
    u32 xr = (u32)((r & 7) << 4);
    float s = 0.f;
#pragma unroll
    for (int kk = 0; kk < 128; kk += 8) {
      int k = seg * 128 + kk;
      f16x8 v = *reinterpret_cast<const f16x8*>(hb + ((rb + (u32)(k * 2)) ^ xr));
#pragma unroll
      for (int j = 0; j < 8; ++j) s = fmaf((float)v[j], W4[k + j], s);
    }
    partials[seg * 64 + r] = s;
  }
  __syncthreads();
  if (tid < ROWS) {
    float s = b4[0];
#pragma unroll
    for (int g = 0; g < 8; ++g) s += partials[g * 64 + tid];
    out[r0 + tid] = s;
  }
}

extern "C" void kernel_launch(void* const* d_in, const int* in_sizes, int n_in,
                              void* d_out, int out_size, void* d_ws, size_t ws_size,
                              hipStream_t stream) {
  const float* X  = (const float*)d_in[0];
  const float* lb = (const float*)d_in[1];
  const float* ub = (const float*)d_in[2];
  const float* W0 = (const float*)d_in[3];
  const float* b0 = (const float*)d_in[4];
  const float* W1 = (const float*)d_in[5];
  const float* b1 = (const float*)d_in[6];
  const float* W2 = (const float*)d_in[7];
  const float* b2 = (const float*)d_in[8];
  const float* W3 = (const float*)d_in[9];
  const float* b3 = (const float*)d_in[10];
  const float* W4 = (const float*)d_in[11];
  const float* b4 = (const float*)d_in[12];
  float* out = (float*)d_out;

  _Float16* WF1 = (_Float16*)d_ws;                                    // 2 MiB
  _Float16* WF2 = (_Float16*)((char*)d_ws + 2097152);                 // 1 MiB
  _Float16* WF3 = (_Float16*)((char*)d_ws + 2097152 + 1048576);       // 512 KiB

  hipLaunchKernelGGL(pack_weights, dim3(448), dim3(512), 0, stream,
                     W1, W2, W3, WF1, WF2, WF3);
  hipLaunchKernelGGL(bspinn_fused, dim3(131072 / ROWS), dim3(THREADS), 0, stream,
                     X, lb, ub, W0, b0, WF1, b1, WF2, b2, WF3, b3, W4, b4, out);
}

// Round 6
// 482.837 us; speedup vs baseline: 1.4938x; 1.0177x over previous
//
#include <hip/hip_runtime.h>

typedef _Float16 f16x8 __attribute__((ext_vector_type(8)));
typedef _Float16 f16x4 __attribute__((ext_vector_type(4)));
typedef __fp16  fp16x2 __attribute__((ext_vector_type(2)));
typedef float f32x4 __attribute__((ext_vector_type(4)));
typedef unsigned int u32;

#define ROWS 64
#define THREADS 512

// ---------------------------------------------------------------------------
// Prep: convert W1/W2/W3 (f32, [K][C] row-major) into f16 fragment-linear
// layout WF[ct][kt][lane][8], applying block-diag masks by only gathering
// in-block K. Fragment mapping (used as MFMA *A* operand, M-dim = out col):
//   col = ct*16 + (lane&15), k = kbase + kt*32 + (lane>>4)*8 + j
// ---------------------------------------------------------------------------
__global__ __launch_bounds__(512) void pack_weights(
    const float* __restrict__ W1, const float* __restrict__ W2,
    const float* __restrict__ W3, _Float16* __restrict__ WF1,
    _Float16* __restrict__ WF2, _Float16* __restrict__ WF3) {
  int t = blockIdx.x * 512 + threadIdx.x;
  const float* src; _Float16* dst; int idx, ct, kt, lane, kbase;
  if (t < 131072) {                       // W1: 64 ct * 32 kt * 64 lanes
    idx = t; src = W1; dst = WF1;
    ct = idx >> 11; kt = (idx >> 6) & 31; lane = idx & 63; kbase = 0;
  } else if (t < 196608) {                // W2: 64 ct * 16 kt * 64 lanes
    idx = t - 131072; src = W2; dst = WF2;
    ct = idx >> 10; kt = (idx >> 6) & 15; lane = idx & 63;
    kbase = (ct >= 32) ? 512 : 0;         // 2 blocks of 512
  } else {                                // W3: 64 ct * 8 kt * 64 lanes
    idx = t - 196608; src = W3; dst = WF3;
    ct = idx >> 9; kt = (idx >> 6) & 7; lane = idx & 63;
    kbase = (ct >> 4) << 8;               // 4 blocks of 256
  }
  int c  = ct * 16 + (lane & 15);
  int k0 = kbase + kt * 32 + ((lane >> 4) << 3);
  f16x8 v;
#pragma unroll
  for (int j = 0; j < 8; ++j) v[j] = (_Float16)src[(size_t)(k0 + j) * 1024 + c];
  *reinterpret_cast<f16x8*>(dst + (size_t)idx * 8) = v;
}

// ---------------------------------------------------------------------------
// One MFMA layer, TRANSPOSED operand order: D = W_frag * h_frag.
//   A (W): M-dim = out col,  row = lane&15, k = kt*32+(lane>>4)*8+j
//   B (h): N-dim = data row, col = lane&15, same k mapping (ds_read_b128)
//   D:     col(lane&15) = data row r, row((lane>>4)*4+i) = out col c
// Wave wid owns out-cols [wid*128, +128): acc[8 cf][4 rf] (AGPRs).
// W is software-pipelined 1 phase deep (global->reg dbuf, counted vmcnt);
// h fragments are single-buffered (ds_read latency covered by MFMA cluster).
// Budget note: 8 waves/WG => 2 waves/SIMD => 256 unified regs/wave.
// acc = 128 AGPR; live VGPRs must stay < 128 (round-5 h-dbuf spilled).
// ---------------------------------------------------------------------------
template <int KT>
__device__ __forceinline__ void layer_mfma(char* hb, const _Float16* __restrict__ WF,
                                           const float* __restrict__ bias,
                                           int wid, int lane, int kbase) {
  f32x4 acc[8][4];
#pragma unroll
  for (int cf = 0; cf < 8; ++cf)
#pragma unroll
    for (int rf = 0; rf < 4; ++rf) acc[cf][rf] = f32x4{0.f, 0.f, 0.f, 0.f};

  const f16x8* wf = reinterpret_cast<const f16x8*>(WF) +
                    (u32)(wid * 8 * KT * 64 + lane);
  const int arow = lane & 15;
  const int koff = (lane >> 4) << 3;
  const u32 abase = (u32)(arow * 2048);
  const u32 axor  = (u32)((arow & 7) << 4);   // (row&7)==(arow&7): rf*16 ≡ 0 mod 8

  f16x8 wA[8], wB[8];
#define LOADW(buf, ktv)                                                        \
  { u32 _kt = (u32)(ktv);                                                      \
    _Pragma("unroll") for (int cf = 0; cf < 8; ++cf)                           \
      buf[cf] = wf[(u32)(cf * KT) * 64u + _kt * 64u]; }
#define DOMFMA(w, ktv)                                                         \
  { u32 kb = (u32)((kbase + (ktv) * 32 + koff) * 2);                           \
    f16x8 h[4];                                                                \
    _Pragma("unroll") for (int rf = 0; rf < 4; ++rf) {                         \
      u32 addr = ((u32)(rf * 32768) + abase + kb) ^ axor;                      \
      h[rf] = *reinterpret_cast<const f16x8*>(hb + addr);                      \
    }                                                                          \
    __builtin_amdgcn_s_setprio(1);                                             \
    _Pragma("unroll") for (int cf = 0; cf < 8; ++cf)                           \
      _Pragma("unroll") for (int rf = 0; rf < 4; ++rf)                         \
        acc[cf][rf] = __builtin_amdgcn_mfma_f32_16x16x32_f16(w[cf], h[rf],     \
                                                             acc[cf][rf], 0, 0, 0); \
    __builtin_amdgcn_s_setprio(0); }

  LOADW(wA, 0);
#pragma unroll 1
  for (int kt = 0; kt < KT; kt += 2) {
    int ktn = (kt + 2 < KT) ? (kt + 2) : 0;
    LOADW(wB, kt + 1);                    // issue next-phase W loads first
    DOMFMA(wA, kt);                       // ds_read h + 32 MFMA (counted waits)
    LOADW(wA, ktn);
    DOMFMA(wB, kt + 1);
  }
#undef LOADW
#undef DOMFMA

  __syncthreads();                          // all waves done READING h
  const int csub = (lane >> 4) << 2;        // 0,4,8,12
  const int rr   = lane & 15;
#pragma unroll
  for (int cf = 0; cf < 8; ++cf) {
    int c0 = wid * 128 + cf * 16 + csub;
    f32x4 bb = *reinterpret_cast<const f32x4*>(bias + c0);
#pragma unroll
    for (int rf = 0; rf < 4; ++rf) {
      int r = rf * 16 + rr;
      float s0 = __sinf(acc[cf][rf][0] + bb[0]);
      float s1 = __sinf(acc[cf][rf][1] + bb[1]);
      float s2 = __sinf(acc[cf][rf][2] + bb[2]);
      float s3 = __sinf(acc[cf][rf][3] + bb[3]);
      union { fp16x2 h2[2]; f16x4 v; } pk;
      pk.h2[0] = __builtin_amdgcn_cvt_pkrtz(s0, s1);
      pk.h2[1] = __builtin_amdgcn_cvt_pkrtz(s2, s3);
      u32 addr = ((u32)(r * 2048 + c0 * 2)) ^ ((u32)((r & 7) << 4));
      *reinterpret_cast<f16x4*>(hb + addr) = pk.v;
    }
  }
  __syncthreads();                          // h_out visible before next layer
}

// ---------------------------------------------------------------------------
// Fused forward: 64 rows per WG, h lives in LDS for the whole network.
// ---------------------------------------------------------------------------
__global__
__attribute__((amdgpu_flat_work_group_size(512, 512), amdgpu_waves_per_eu(2, 2)))
void bspinn_fused(
    const float* __restrict__ X, const float* __restrict__ lb,
    const float* __restrict__ ub,
    const float* __restrict__ W0, const float* __restrict__ b0,
    const _Float16* __restrict__ WF1, const float* __restrict__ b1,
    const _Float16* __restrict__ WF2, const float* __restrict__ b2,
    const _Float16* __restrict__ WF3, const float* __restrict__ b3,
    const float* __restrict__ W4, const float* __restrict__ b4,
    float* __restrict__ out) {
  __shared__ alignas(16) char hb[ROWS * 2048];   // 128 KiB, f16, swizzled
  __shared__ float xs[ROWS * 4];
  __shared__ float partials[ROWS * 8];

  const int tid  = threadIdx.x;
  const int lane = tid & 63;
  const int wid  = tid >> 6;
  const int r0   = blockIdx.x * ROWS;

  if (tid < ROWS * 3) {                      // stage + normalize X
    int r = tid / 3, j = tid - r * 3;
    float x = X[(size_t)r0 * 3 + tid];
    xs[r * 4 + j] = 2.0f * (x - lb[j]) / (ub[j] - lb[j]) - 1.0f;
  }
  __syncthreads();

  // ---- layer 1 (K=3, VALU): each thread owns 2 cols x 64 rows ----
  {
    int c0 = tid * 2;
    float wa0 = W0[c0],        wb0 = W0[c0 + 1];
    float wa1 = W0[1024 + c0], wb1 = W0[1025 + c0];
    float wa2 = W0[2048 + c0], wb2 = W0[2049 + c0];
    float ba = b0[c0], bbv = b0[c0 + 1];
#pragma unroll 4
    for (int r = 0; r < ROWS; ++r) {
      float x0 = xs[r * 4], x1 = xs[r * 4 + 1], x2 = xs[r * 4 + 2];
      float va = __sinf(fmaf(x2, wa2, fmaf(x1, wa1, fmaf(x0, wa0, ba))));
      float vb = __sinf(fmaf(x2, wb2, fmaf(x1, wb1, fmaf(x0, wb0, bbv))));
      union { fp16x2 h2; u32 u; } pk;
      pk.h2 = __builtin_amdgcn_cvt_pkrtz(va, vb);
      u32 addr = ((u32)(r * 2048 + c0 * 2)) ^ ((u32)((r & 7) << 4));
      *reinterpret_cast<u32*>(hb + addr) = pk.u;
    }
  }
  __syncthreads();

  layer_mfma<32>(hb, WF1, b1, wid, lane, 0);                  // dense 1024
  layer_mfma<16>(hb, WF2, b2, wid, lane, (wid >> 2) * 512);   // 2 blocks
  layer_mfma<8 >(hb, WF3, b3, wid, lane, (wid >> 1) * 256);   // 4 blocks

  // ---- layer 5 (M=1, VALU): lane = row -> swizzled conflict-light reads ----
  {
    int r = lane, seg = wid;
    u32 rb = (u32)(r * 2048);
    u32 xr = (u32)((r & 7) << 4);
    float s = 0.f;
#pragma unroll
    for (int kk = 0; kk < 128; kk += 8) {
      int k = seg * 128 + kk;
      f16x8 v = *reinterpret_cast<const f16x8*>(hb + ((rb + (u32)(k * 2)) ^ xr));
#pragma unroll
      for (int j = 0; j < 8; ++j) s = fmaf((float)v[j], W4[k + j], s);
    }
    partials[seg * 64 + r] = s;
  }
  __syncthreads();
  if (tid < ROWS) {
    float s = b4[0];
#pragma unroll
    for (int g = 0; g < 8; ++g) s += partials[g * 64 + tid];
    out[r0 + tid] = s;
  }
}

extern "C" void kernel_launch(void* const* d_in, const int* in_sizes, int n_in,
                              void* d_out, int out_size, void* d_ws, size_t ws_size,
                              hipStream_t stream) {
  const float* X  = (const float*)d_in[0];
  const float* lb = (const float*)d_in[1];
  const float* ub = (const float*)d_in[2];
  const float* W0 = (const float*)d_in[3];
  const float* b0 = (const float*)d_in[4];
  const float* W1 = (const float*)d_in[5];
  const float* b1 = (const float*)d_in[6];
  const float* W2 = (const float*)d_in[7];
  const float* b2 = (const float*)d_in[8];
  const float* W3 = (const float*)d_in[9];
  const float* b3 = (const float*)d_in[10];
  const float* W4 = (const float*)d_in[11];
  const float* b4 = (const float*)d_in[12];
  float* out = (float*)d_out;

  _Float16* WF1 = (_Float16*)d_ws;                                    // 2 MiB
  _Float16* WF2 = (_Float16*)((char*)d_ws + 2097152);                 // 1 MiB
  _Float16* WF3 = (_Float16*)((char*)d_ws + 2097152 + 1048576);       // 512 KiB

  hipLaunchKernelGGL(pack_weights, dim3(448), dim3(512), 0, stream,
                     W1, W2, W3, WF1, WF2, WF3);
  hipLaunchKernelGGL(bspinn_fused, dim3(131072 / ROWS), dim3(THREADS), 0, stream,
                     X, lb, ub, W0, b0, WF1, b1, WF2, b2, WF3, b3, W4, b4, out);
}